// Round 10
// baseline (167.603 us; speedup 1.0000x reference)
//
#include <hip/hip_runtime.h>
#include <stdint.h>

// Problem geometry
#define DD    64          // slices
#define HH    512         // rows
#define WWID  512         // cols
#define WPR   8           // u64 words per row (512 bits)
#define NSUB  48          // 24 full iterations x 2 sub-iterations
#define BANDS 8           // row-bands per slice (512 blocks = 2 blocks/CU)
#define BH    64          // output rows per band
#define HALO  52          // 48 (thinning) + 4 (closing)
#define MAXR  (BH + 2*HALO)   // 168 live rows max
#define ARR   (MAXR + 4)      // +2 guard rows each side = 172
#define PITCH 10              // guard word 0, live 1..8, guard word 9
#define NTHR  384             // 6 waves; 168 rows x 2 halves = 336 active

typedef unsigned long long u64;

// ---------------- kernel 1: threshold + bit-pack via ballot ----------------
__global__ void pack_kernel(const float* __restrict__ in, u64* __restrict__ bits) {
    long gid  = (long)blockIdx.x * blockDim.x + threadIdx.x;
    long wv   = gid >> 6;
    int  lane = (int)(gid & 63);
    long base = wv * 256;
    #pragma unroll
    for (int k = 0; k < 4; ++k) {
        float v = in[base + (long)k * 64 + lane];
        u64 m = __ballot(v > 0.5f);
        if (lane == 0) bits[wv * 4 + k] = m;
    }
}

// Zhang-Suen delete test for one 64-pixel word, bit-sliced. sub is a literal.
__device__ __forceinline__ u64 zs_word(u64 c, u64 N, u64 NE, u64 E, u64 SE,
                                       u64 S, u64 SW, u64 Wn, u64 NW, int sub) {
    u64 t0 = ~N  & NE;
    u64 t1 = ~NE & E;
    u64 t2 = ~E  & SE;
    u64 t3 = ~SE & S;
    u64 t4 = ~S  & SW;
    u64 t5 = ~SW & Wn;
    u64 t6 = ~Wn & NW;
    u64 t7 = ~NW & N;
    u64 o01 = t0 ^ t1, w01 = t0 & t1;
    u64 o23 = t2 ^ t3, w23 = t2 & t3;
    u64 o45 = t4 ^ t5, w45 = t4 & t5;
    u64 o67 = t6 ^ t7, w67 = t6 & t7;
    u64 oA = o01 ^ o23, wA = w01 | w23 | (o01 & o23);
    u64 oB = o45 ^ o67, wB = w45 | w67 | (o45 & o67);
    u64 A1 = (oA ^ oB) & ~(wA | wB | (oA & oB));
    u64 sa, ca; { u64 tt = N ^ NE; sa = tt ^ E;  ca = (N & NE) | (tt & E);  }
    u64 sb, cb; { u64 tt = SE ^ S; sb = tt ^ SW; cb = (SE & S) | (tt & SW); }
    u64 sc = Wn ^ NW, cc = Wn & NW;
    u64 S0, cd; { u64 tt = sa ^ sb; S0 = tt ^ sc;  cd = (sa & sb) | (tt & sc); }
    u64 t2s, ce; { u64 tt = ca ^ cb; t2s = tt ^ cc; ce = (ca & cb) | (tt & cc); }
    u64 S1 = cd ^ t2s, cf = cd & t2s;
    u64 S2 = ce ^ cf,  S3 = ce & cf;
    u64 cB = (S1 | S2 | S3) & ~((S2 & S1 & S0) | S3);
    u64 c3, c4;
    if (sub == 0) { c3 = ~(N & E & S);  c4 = ~(E & S & Wn); }
    else          { c3 = ~(N & E & Wn); c4 = ~(N & S & Wn); }
    return c & ~(cB & A1 & c3 & c4);
}

// One closing phase with compile-time buffers. ISDIL literal.
#define CLOSE_PHASE(SRC, DST, ISDIL, SETREG) do {                                       \
    if (lr < nrows) {                                                                   \
        u64 w_[5][6];                                                                   \
        _Pragma("unroll") for (int rr = 0; rr < 5; ++rr) {                              \
            ulonglong2 va = *reinterpret_cast<const ulonglong2*>(&SRC[ar-2+rr][h4]);    \
            ulonglong2 vb = *reinterpret_cast<const ulonglong2*>(&SRC[ar-2+rr][h4+2]);  \
            ulonglong2 vc = *reinterpret_cast<const ulonglong2*>(&SRC[ar-2+rr][h4+4]);  \
            w_[rr][0]=va.x; w_[rr][1]=va.y; w_[rr][2]=vb.x;                             \
            w_[rr][3]=vb.y; w_[rr][4]=vc.x; w_[rr][5]=vc.y;                             \
        }                                                                               \
        _Pragma("unroll") for (int jj = 0; jj < 4; ++jj) {                              \
            u64 c=w_[2][jj+1], pl=w_[2][jj], pr=w_[2][jj+2];                            \
            u64 l1=(c<<1)|(pl>>63), l2=(c<<2)|(pl>>62);                                 \
            u64 q1=(c>>1)|(pr<<63), q2=(c>>2)|(pr<<62);                                 \
            u64 u_=w_[1][jj+1], ul=(u_<<1)|(w_[1][jj]>>63), ur=(u_>>1)|(w_[1][jj+2]<<63);\
            u64 d_=w_[3][jj+1], dl=(d_<<1)|(w_[3][jj]>>63), dr=(d_>>1)|(w_[3][jj+2]<<63);\
            u64 u2=w_[0][jj+1], d2=w_[4][jj+1];                                         \
            u64 r_ = ISDIL ? (c|l1|l2|q1|q2|u_|ul|ur|d_|dl|dr|u2|d2)                    \
                           : (c&l1&l2&q1&q2&u_&ul&ur&d_&dl&dr&u2&d2);                   \
            DST[ar][h4+1+jj] = r_;                                                      \
            if (SETREG) { if (jj==0) myw0=r_; else if (jj==1) myw1=r_;                  \
                          else if (jj==2) myw2=r_; else myw3=r_; }                      \
        }                                                                               \
    }                                                                                   \
    __syncthreads();                                                                    \
} while (0)

// One thinning sub-iteration: center row from registers, compile-time buffers.
#define THIN_SUB(SRC, DST, SUB, LO, HI) do {                                            \
    if (lr >= (LO) && lr < (HI)) {                                                      \
        ulonglong2 ua = *reinterpret_cast<const ulonglong2*>(&SRC[ar-1][h4]);           \
        ulonglong2 ub = *reinterpret_cast<const ulonglong2*>(&SRC[ar-1][h4+2]);         \
        ulonglong2 uc = *reinterpret_cast<const ulonglong2*>(&SRC[ar-1][h4+4]);         \
        ulonglong2 da = *reinterpret_cast<const ulonglong2*>(&SRC[ar+1][h4]);           \
        ulonglong2 db = *reinterpret_cast<const ulonglong2*>(&SRC[ar+1][h4+2]);         \
        ulonglong2 dc = *reinterpret_cast<const ulonglong2*>(&SRC[ar+1][h4+4]);         \
        u64 edge = SRC[ar][5 - h];                                                      \
        u64 uu0=ua.x, uu1=ua.y, uu2=ub.x, uu3=ub.y, uu4=uc.x, uu5=uc.y;                 \
        u64 dd0=da.x, dd1=da.y, dd2=db.x, dd3=db.y, dd4=dc.x, dd5=dc.y;                 \
        u64 lw = h ? edge : 0ull;                                                       \
        u64 rw = h ? 0ull : edge;                                                       \
        u64 r0_, r1_, r2_, r3_;                                                         \
        { u64 c=myw0, pl=lw, pr=myw1;                                                   \
          u64 E=(c>>1)|(pr<<63), Wn=(c<<1)|(pl>>63);                                    \
          u64 NE=(uu1>>1)|(uu2<<63), NW=(uu1<<1)|(uu0>>63);                             \
          u64 SE=(dd1>>1)|(dd2<<63), SW=(dd1<<1)|(dd0>>63);                             \
          r0_ = zs_word(c, uu1, NE, E, SE, dd1, SW, Wn, NW, SUB); }                     \
        { u64 c=myw1, pl=myw0, pr=myw2;                                                 \
          u64 E=(c>>1)|(pr<<63), Wn=(c<<1)|(pl>>63);                                    \
          u64 NE=(uu2>>1)|(uu3<<63), NW=(uu2<<1)|(uu1>>63);                             \
          u64 SE=(dd2>>1)|(dd3<<63), SW=(dd2<<1)|(dd1>>63);                             \
          r1_ = zs_word(c, uu2, NE, E, SE, dd2, SW, Wn, NW, SUB); }                     \
        { u64 c=myw2, pl=myw1, pr=myw3;                                                 \
          u64 E=(c>>1)|(pr<<63), Wn=(c<<1)|(pl>>63);                                    \
          u64 NE=(uu3>>1)|(uu4<<63), NW=(uu3<<1)|(uu2>>63);                             \
          u64 SE=(dd3>>1)|(dd4<<63), SW=(dd3<<1)|(dd2>>63);                             \
          r2_ = zs_word(c, uu3, NE, E, SE, dd3, SW, Wn, NW, SUB); }                     \
        { u64 c=myw3, pl=myw2, pr=rw;                                                   \
          u64 E=(c>>1)|(pr<<63), Wn=(c<<1)|(pl>>63);                                    \
          u64 NE=(uu4>>1)|(uu5<<63), NW=(uu4<<1)|(uu3>>63);                             \
          u64 SE=(dd4>>1)|(dd5<<63), SW=(dd4<<1)|(dd3>>63);                             \
          r3_ = zs_word(c, uu4, NE, E, SE, dd4, SW, Wn, NW, SUB); }                     \
        DST[ar][h4+1]=r0_; DST[ar][h4+2]=r1_; DST[ar][h4+3]=r2_; DST[ar][h4+4]=r3_;     \
        myw0=r0_; myw1=r1_; myw2=r2_; myw3=r3_;                                         \
    }                                                                                   \
    __syncthreads();                                                                    \
} while (0)

// ---------------- kernel 2: closing + 48x thinning in LDS ----------------
// One block per (slice, 64-row band); 512 blocks = 2 blocks/CU so one block's
// barrier drain overlaps the other block's compute.
__global__ __launch_bounds__(NTHR, 3)
void thin_kernel(const u64* __restrict__ bits, int* __restrict__ out) {
    __shared__ u64 bufA[ARR][PITCH];
    __shared__ u64 bufB[ARR][PITCH];

    const int blk  = blockIdx.x;
    const int z    = blk >> 3;       // slice
    const int band = blk & 7;
    const int r0   = band * BH;      // first output row
    const int la   = (r0 - HALO > 0) ? (r0 - HALO) : 0;
    const int lb   = (r0 + BH + HALO < HH) ? (r0 + BH + HALO) : HH;
    const int nrows = lb - la;       // live rows (<= 168)
    const int ob0  = r0 - la;        // local output start (0 or 52)

    const int t  = threadIdx.x;
    const int lr = t >> 1;           // live row handled by this thread
    const int h  = t & 1;            // column half
    const int h4 = h * 4;            // live word offset: 0 or 4
    const int ar = lr + 2;           // array row (2 guard rows at top)

    u64 myw0 = 0, myw1 = 0, myw2 = 0, myw3 = 0;   // register-resident center row

    // ---- zero both buffers (guards must be 0 in both) ----
    {
        u64* fa = &bufA[0][0];
        u64* fb = &bufB[0][0];
        for (int i = t; i < ARR * PITCH; i += NTHR) { fa[i] = 0; fb[i] = 0; }
    }
    __syncthreads();

    // ---- load packed raw mask into bufA live area ----
    if (lr < nrows) {
        const u64* src = bits + ((long)(z * HH + la + lr)) * WPR + h4;
        ulonglong2 v0 = *reinterpret_cast<const ulonglong2*>(src);
        ulonglong2 v1 = *reinterpret_cast<const ulonglong2*>(src + 2);
        bufA[ar][h4 + 1] = v0.x;
        bufA[ar][h4 + 2] = v0.y;
        bufA[ar][h4 + 3] = v1.x;
        bufA[ar][h4 + 4] = v1.y;
    }
    __syncthreads();

    // ---- closing: dilation (A->B) then erosion (B->A, seeds registers) ----
    CLOSE_PHASE(bufA, bufB, 1, 0);
    CLOSE_PHASE(bufB, bufA, 0, 1);

    // ---- 48 Zhang-Suen sub-iterations, shrinking active range ----
    #pragma unroll 1
    for (int it2 = 0; it2 < NSUB / 2; ++it2) {
        {
            int hw = NSUB - (2 * it2 + 1);
            int lo = ob0 - hw;       if (lo < 0) lo = 0;
            int hi = ob0 + BH + hw;  if (hi > nrows) hi = nrows;
            THIN_SUB(bufA, bufB, 0, lo, hi);
        }
        {
            int hw = NSUB - (2 * it2 + 2);
            int lo = ob0 - hw;       if (lo < 0) lo = 0;
            int hi = ob0 + BH + hw;  if (hi > nrows) hi = nrows;
            THIN_SUB(bufB, bufA, 1, lo, hi);
        }
    }
    // final state is in bufA

    // ---- expand band rows [r0, r0+BH) to int32 0/1, coalesced int4 stores ----
    const long slice_base = (long)z * HH * WWID;
    for (int e = t; e < BH * (WWID / 4); e += NTHR) {
        int rr  = e >> 7;
        int x4  = e & 127;
        int gr  = r0 + rr;
        int arr = (gr - la) + 2;
        int col = x4 * 4;
        u64 w  = bufA[arr][1 + (col >> 6)];
        int sh = col & 63;
        int4 f;
        f.x = (int)((w >> (sh + 0)) & 1ull);
        f.y = (int)((w >> (sh + 1)) & 1ull);
        f.z = (int)((w >> (sh + 2)) & 1ull);
        f.w = (int)((w >> (sh + 3)) & 1ull);
        *reinterpret_cast<int4*>(out + slice_base + (long)gr * WWID + col) = f;
    }
}

extern "C" void kernel_launch(void* const* d_in, const int* in_sizes, int n_in,
                              void* d_out, int out_size, void* d_ws, size_t ws_size,
                              hipStream_t stream) {
    const float* in   = (const float*)d_in[0];
    int*         out  = (int*)d_out;
    u64*         bits = (u64*)d_ws;   // 2 MiB scratch

    pack_kernel<<<16384, 256, 0, stream>>>(in, bits);
    thin_kernel<<<DD * BANDS, NTHR, 0, stream>>>(bits, out);
}

// Round 11
// 121.077 us; speedup vs baseline: 1.3843x; 1.3843x over previous
//
#include <hip/hip_runtime.h>
#include <stdint.h>

// Problem geometry
#define DD    64          // slices
#define HH    512         // rows
#define WWID  512         // cols
#define WPR   8           // u64 words per row (512 bits)
#define NSUB  48          // 24 full iterations x 2 sub-iterations
#define BANDS 4           // row-bands per slice
#define BH    128         // output rows per band
#define HALO  52          // 48 (thinning) + 4 (closing)
#define MAXR  (BH + 2*HALO)   // 232 live rows max
#define ARR   (MAXR + 4)      // +2 guard rows each side = 236
#define PITCH 14              // 112B row stride: 2-way bank aliasing, 16B-aligned even idx
#define WOFF  2               // word j lives at LDS idx j+WOFF; guards idx 1 and 10
#define NTHR  1024            // 4 threads/row: 232 rows x 4 = 928 active, 16 waves

typedef unsigned long long u64;

// ---------------- kernel 1: threshold + bit-pack via ballot ----------------
__global__ void pack_kernel(const float* __restrict__ in, u64* __restrict__ bits) {
    long gid  = (long)blockIdx.x * blockDim.x + threadIdx.x;
    long wv   = gid >> 6;
    int  lane = (int)(gid & 63);
    long base = wv * 256;
    #pragma unroll
    for (int k = 0; k < 4; ++k) {
        float v = in[base + (long)k * 64 + lane];
        u64 m = __ballot(v > 0.5f);
        if (lane == 0) bits[wv * 4 + k] = m;
    }
}

// Zhang-Suen delete test for one 64-pixel word, bit-sliced. sub is a literal.
__device__ __forceinline__ u64 zs_word(u64 c, u64 N, u64 NE, u64 E, u64 SE,
                                       u64 S, u64 SW, u64 Wn, u64 NW, int sub) {
    u64 t0 = ~N  & NE;
    u64 t1 = ~NE & E;
    u64 t2 = ~E  & SE;
    u64 t3 = ~SE & S;
    u64 t4 = ~S  & SW;
    u64 t5 = ~SW & Wn;
    u64 t6 = ~Wn & NW;
    u64 t7 = ~NW & N;
    u64 o01 = t0 ^ t1, w01 = t0 & t1;
    u64 o23 = t2 ^ t3, w23 = t2 & t3;
    u64 o45 = t4 ^ t5, w45 = t4 & t5;
    u64 o67 = t6 ^ t7, w67 = t6 & t7;
    u64 oA = o01 ^ o23, wA = w01 | w23 | (o01 & o23);
    u64 oB = o45 ^ o67, wB = w45 | w67 | (o45 & o67);
    u64 A1 = (oA ^ oB) & ~(wA | wB | (oA & oB));
    u64 sa, ca; { u64 tt = N ^ NE; sa = tt ^ E;  ca = (N & NE) | (tt & E);  }
    u64 sb, cb; { u64 tt = SE ^ S; sb = tt ^ SW; cb = (SE & S) | (tt & SW); }
    u64 sc = Wn ^ NW, cc = Wn & NW;
    u64 S0, cd; { u64 tt = sa ^ sb; S0 = tt ^ sc;  cd = (sa & sb) | (tt & sc); }
    u64 t2s, ce; { u64 tt = ca ^ cb; t2s = tt ^ cc; ce = (ca & cb) | (tt & cc); }
    u64 S1 = cd ^ t2s, cf = cd & t2s;
    u64 S2 = ce ^ cf,  S3 = ce & cf;
    u64 cB = (S1 | S2 | S3) & ~((S2 & S1 & S0) | S3);
    u64 c3, c4;
    if (sub == 0) { c3 = ~(N & E & S);  c4 = ~(E & S & Wn); }
    else          { c3 = ~(N & E & Wn); c4 = ~(N & S & Wn); }
    return c & ~(cB & A1 & c3 & c4);
}

// Closing phase: this thread owns words 2q (A) and 2q+1 (B) of its row.
// Span s_[rr][0..5] = words 2q-2 .. 2q+3 of row ar-2+rr.
#define CLOSE_PHASE(SRC, DST, ISDIL, SETREG) do {                                       \
    if (act) {                                                                          \
        u64 s_[5][6];                                                                   \
        _Pragma("unroll") for (int rr = 0; rr < 5; ++rr) {                              \
            ulonglong2 v0 = *reinterpret_cast<const ulonglong2*>(&SRC[ar-2+rr][wb-2]);  \
            ulonglong2 v1 = *reinterpret_cast<const ulonglong2*>(&SRC[ar-2+rr][wb]);    \
            ulonglong2 v2 = *reinterpret_cast<const ulonglong2*>(&SRC[ar-2+rr][wb+2]);  \
            s_[rr][0]=v0.x; s_[rr][1]=v0.y; s_[rr][2]=v1.x;                             \
            s_[rr][3]=v1.y; s_[rr][4]=v2.x; s_[rr][5]=v2.y;                             \
        }                                                                               \
        u64 rA, rB;                                                                     \
        _Pragma("unroll") for (int jj = 0; jj < 2; ++jj) {                              \
            u64 c  = s_[2][jj+2], pl = s_[2][jj+1], pr = s_[2][jj+3];                   \
            u64 l1 = (c<<1)|(pl>>63), l2 = (c<<2)|(pl>>62);                             \
            u64 r1 = (c>>1)|(pr<<63), r2 = (c>>2)|(pr<<62);                             \
            u64 u_ = s_[1][jj+2], ul = (u_<<1)|(s_[1][jj+1]>>63), ur = (u_>>1)|(s_[1][jj+3]<<63);\
            u64 d_ = s_[3][jj+2], dl = (d_<<1)|(s_[3][jj+1]>>63), dr = (d_>>1)|(s_[3][jj+3]<<63);\
            u64 u2 = s_[0][jj+2], d2 = s_[4][jj+2];                                     \
            u64 r_ = ISDIL ? (c|l1|l2|r1|r2|u_|ul|ur|d_|dl|dr|u2|d2)                    \
                           : (c&l1&l2&r1&r2&u_&ul&ur&d_&dl&dr&u2&d2);                   \
            if (jj == 0) rA = r_; else rB = r_;                                         \
        }                                                                               \
        ulonglong2 st; st.x = rA; st.y = rB;                                            \
        *reinterpret_cast<ulonglong2*>(&DST[ar][wb]) = st;                              \
        if (SETREG) { myw0 = rA; myw1 = rB; }                                           \
    }                                                                                   \
    __syncthreads();                                                                    \
} while (0)

// One thinning sub-iteration: center words from registers.
#define THIN_SUB(SRC, DST, SUB, LO, HI) do {                                            \
    if (act && lr >= (LO) && lr < (HI)) {                                               \
        ulonglong2 u0 = *reinterpret_cast<const ulonglong2*>(&SRC[ar-1][wb-2]);         \
        ulonglong2 u1 = *reinterpret_cast<const ulonglong2*>(&SRC[ar-1][wb]);           \
        ulonglong2 u2 = *reinterpret_cast<const ulonglong2*>(&SRC[ar-1][wb+2]);         \
        ulonglong2 d0 = *reinterpret_cast<const ulonglong2*>(&SRC[ar+1][wb-2]);         \
        ulonglong2 d1 = *reinterpret_cast<const ulonglong2*>(&SRC[ar+1][wb]);           \
        ulonglong2 d2 = *reinterpret_cast<const ulonglong2*>(&SRC[ar+1][wb+2]);         \
        ulonglong2 cl = *reinterpret_cast<const ulonglong2*>(&SRC[ar][wb-2]);           \
        ulonglong2 cr = *reinterpret_cast<const ulonglong2*>(&SRC[ar][wb+2]);           \
        u64 rA, rB;                                                                     \
        { u64 c = myw0, pl = cl.y, pr = myw1;                                           \
          u64 N  = u1.x, S = d1.x;                                                      \
          u64 E  = (c>>1)|(pr<<63),   Wn = (c<<1)|(pl>>63);                             \
          u64 NE = (u1.x>>1)|(u1.y<<63), NW = (u1.x<<1)|(u0.y>>63);                     \
          u64 SE = (d1.x>>1)|(d1.y<<63), SW = (d1.x<<1)|(d0.y>>63);                     \
          rA = zs_word(c, N, NE, E, SE, S, SW, Wn, NW, SUB); }                          \
        { u64 c = myw1, pl = myw0, pr = cr.x;                                           \
          u64 N  = u1.y, S = d1.y;                                                      \
          u64 E  = (c>>1)|(pr<<63),   Wn = (c<<1)|(pl>>63);                             \
          u64 NE = (u1.y>>1)|(u2.x<<63), NW = (u1.y<<1)|(u1.x>>63);                     \
          u64 SE = (d1.y>>1)|(d2.x<<63), SW = (d1.y<<1)|(d1.x>>63);                     \
          rB = zs_word(c, N, NE, E, SE, S, SW, Wn, NW, SUB); }                          \
        ulonglong2 st; st.x = rA; st.y = rB;                                            \
        *reinterpret_cast<ulonglong2*>(&DST[ar][wb]) = st;                              \
        myw0 = rA; myw1 = rB;                                                           \
    }                                                                                   \
    __syncthreads();                                                                    \
} while (0)

// ---------------- kernel 2: closing + 48x thinning in LDS ----------------
// One block per (slice, 128-row band). 1024 threads = 4 threads/row
// (2 u64 words each) = 16 waves = 4 waves/SIMD for latency hiding.
__global__ __launch_bounds__(NTHR, 1)
void thin_kernel(const u64* __restrict__ bits, int* __restrict__ out) {
    __shared__ u64 bufA[ARR][PITCH];
    __shared__ u64 bufB[ARR][PITCH];

    const int blk  = blockIdx.x;
    const int z    = blk >> 2;       // slice
    const int band = blk & 3;
    const int r0   = band * BH;      // first output row
    const int la   = (r0 - HALO > 0) ? (r0 - HALO) : 0;
    const int lb   = (r0 + BH + HALO < HH) ? (r0 + BH + HALO) : HH;
    const int nrows = lb - la;       // live rows (<= 232)
    const int ob0  = r0 - la;        // local output start (0 or 52)

    const int t  = threadIdx.x;
    const int lr = t >> 2;           // row handled by this thread (0..255)
    const int q  = t & 3;            // word-pair index 0..3
    const int wb = 2 * q + WOFF;     // LDS idx of first owned word
    const int ar = lr + 2;           // array row (2 guard rows at top)
    const bool act = (lr < nrows);

    u64 myw0 = 0, myw1 = 0;          // register-resident center words

    // ---- zero both buffers (guards/pads must be 0 in both) ----
    {
        u64* fa = &bufA[0][0];
        u64* fb = &bufB[0][0];
        for (int i = t; i < ARR * PITCH; i += NTHR) { fa[i] = 0; fb[i] = 0; }
    }
    __syncthreads();

    // ---- load packed raw mask into bufA live area ----
    if (act) {
        const u64* src = bits + ((long)(z * HH + la + lr)) * WPR + 2 * q;
        ulonglong2 v = *reinterpret_cast<const ulonglong2*>(src);
        *reinterpret_cast<ulonglong2*>(&bufA[ar][wb]) = v;
    }
    __syncthreads();

    // ---- closing: dilation (A->B) then erosion (B->A, seeds registers) ----
    CLOSE_PHASE(bufA, bufB, 1, 0);
    CLOSE_PHASE(bufB, bufA, 0, 1);

    // ---- 48 Zhang-Suen sub-iterations, shrinking active range ----
    #pragma unroll 1
    for (int it2 = 0; it2 < NSUB / 2; ++it2) {
        {
            int hw = NSUB - (2 * it2 + 1);
            int lo = ob0 - hw;       if (lo < 0) lo = 0;
            int hi = ob0 + BH + hw;  if (hi > nrows) hi = nrows;
            THIN_SUB(bufA, bufB, 0, lo, hi);
        }
        {
            int hw = NSUB - (2 * it2 + 2);
            int lo = ob0 - hw;       if (lo < 0) lo = 0;
            int hi = ob0 + BH + hw;  if (hi > nrows) hi = nrows;
            THIN_SUB(bufB, bufA, 1, lo, hi);
        }
    }
    // final state is in bufA

    // ---- expand band rows [r0, r0+BH) to int32 0/1, coalesced int4 stores ----
    const long slice_base = (long)z * HH * WWID;
    for (int e = t; e < BH * (WWID / 4); e += NTHR) {
        int rr  = e >> 7;
        int x4  = e & 127;
        int gr  = r0 + rr;
        int arr = (gr - la) + 2;
        int col = x4 * 4;
        u64 w  = bufA[arr][WOFF + (col >> 6)];
        int sh = col & 63;
        int4 f;
        f.x = (int)((w >> (sh + 0)) & 1ull);
        f.y = (int)((w >> (sh + 1)) & 1ull);
        f.z = (int)((w >> (sh + 2)) & 1ull);
        f.w = (int)((w >> (sh + 3)) & 1ull);
        *reinterpret_cast<int4*>(out + slice_base + (long)gr * WWID + col) = f;
    }
}

extern "C" void kernel_launch(void* const* d_in, const int* in_sizes, int n_in,
                              void* d_out, int out_size, void* d_ws, size_t ws_size,
                              hipStream_t stream) {
    const float* in   = (const float*)d_in[0];
    int*         out  = (int*)d_out;
    u64*         bits = (u64*)d_ws;   // 2 MiB scratch

    pack_kernel<<<16384, 256, 0, stream>>>(in, bits);
    thin_kernel<<<DD * BANDS, NTHR, 0, stream>>>(bits, out);
}

// Round 12
// 115.219 us; speedup vs baseline: 1.4547x; 1.0508x over previous
//
#include <hip/hip_runtime.h>
#include <stdint.h>

// Problem geometry
#define DD    64          // slices
#define HH    512         // rows
#define WWID  512         // cols
#define WPR   8           // u64 words per row (512 bits)
#define NSUB  48          // 24 full iterations x 2 sub-iterations
#define BANDS 4           // row-bands per slice
#define BH    128         // output rows per band
#define HALO  52          // 48 (thinning) + 4 (closing)
#define MAXR  (BH + 2*HALO)   // 232 live rows max
#define ARR   (MAXR + 4)      // +2 guard rows each side = 236
#define PITCH 12              // 96B stride: bank-group shift 6/row -> uniform x2 per 16-lane clique
#define WOFF  2               // word j at LDS idx j+WOFF; pads 0,11; guards 1,10
#define NTHR  1024            // 4 threads/row (2 u64 words each), 16 waves

typedef unsigned long long u64;

// ---------------- kernel 1: threshold + bit-pack via ballot ----------------
__global__ void pack_kernel(const float* __restrict__ in, u64* __restrict__ bits) {
    long gid  = (long)blockIdx.x * blockDim.x + threadIdx.x;
    long wv   = gid >> 6;
    int  lane = (int)(gid & 63);
    long base = wv * 256;
    #pragma unroll
    for (int k = 0; k < 4; ++k) {
        float v = in[base + (long)k * 64 + lane];
        u64 m = __ballot(v > 0.5f);
        if (lane == 0) bits[wv * 4 + k] = m;
    }
}

// Zhang-Suen delete test for one 64-pixel word, bit-sliced. sub is a literal.
__device__ __forceinline__ u64 zs_word(u64 c, u64 N, u64 NE, u64 E, u64 SE,
                                       u64 S, u64 SW, u64 Wn, u64 NW, int sub) {
    u64 t0 = ~N  & NE;
    u64 t1 = ~NE & E;
    u64 t2 = ~E  & SE;
    u64 t3 = ~SE & S;
    u64 t4 = ~S  & SW;
    u64 t5 = ~SW & Wn;
    u64 t6 = ~Wn & NW;
    u64 t7 = ~NW & N;
    u64 o01 = t0 ^ t1, w01 = t0 & t1;
    u64 o23 = t2 ^ t3, w23 = t2 & t3;
    u64 o45 = t4 ^ t5, w45 = t4 & t5;
    u64 o67 = t6 ^ t7, w67 = t6 & t7;
    u64 oA = o01 ^ o23, wA = w01 | w23 | (o01 & o23);
    u64 oB = o45 ^ o67, wB = w45 | w67 | (o45 & o67);
    u64 A1 = (oA ^ oB) & ~(wA | wB | (oA & oB));
    u64 sa, ca; { u64 tt = N ^ NE; sa = tt ^ E;  ca = (N & NE) | (tt & E);  }
    u64 sb, cb; { u64 tt = SE ^ S; sb = tt ^ SW; cb = (SE & S) | (tt & SW); }
    u64 sc = Wn ^ NW, cc = Wn & NW;
    u64 S0, cd; { u64 tt = sa ^ sb; S0 = tt ^ sc;  cd = (sa & sb) | (tt & sc); }
    u64 t2s, ce; { u64 tt = ca ^ cb; t2s = tt ^ cc; ce = (ca & cb) | (tt & cc); }
    u64 S1 = cd ^ t2s, cf = cd & t2s;
    u64 S2 = ce ^ cf,  S3 = ce & cf;
    u64 cB = (S1 | S2 | S3) & ~((S2 & S1 & S0) | S3);
    u64 c3, c4;
    if (sub == 0) { c3 = ~(N & E & S);  c4 = ~(E & S & Wn); }
    else          { c3 = ~(N & E & Wn); c4 = ~(N & S & Wn); }
    return c & ~(cB & A1 & c3 & c4);
}

// Closing phase: this thread owns words wb (A) and wb+1 (B).
// Reads span words wb-2..wb+3 of rows ar-2..ar+2 (pads/guards are zero).
#define CLOSE_PHASE(SRC, DST, ISDIL, SETREG) do {                                       \
    if (act) {                                                                          \
        u64 s_[5][6];                                                                   \
        _Pragma("unroll") for (int rr = 0; rr < 5; ++rr) {                              \
            ulonglong2 v0 = *reinterpret_cast<const ulonglong2*>(&SRC[ar-2+rr][wb-2]);  \
            ulonglong2 v1 = *reinterpret_cast<const ulonglong2*>(&SRC[ar-2+rr][wb]);    \
            ulonglong2 v2 = *reinterpret_cast<const ulonglong2*>(&SRC[ar-2+rr][wb+2]);  \
            s_[rr][0]=v0.x; s_[rr][1]=v0.y; s_[rr][2]=v1.x;                             \
            s_[rr][3]=v1.y; s_[rr][4]=v2.x; s_[rr][5]=v2.y;                             \
        }                                                                               \
        u64 rA, rB;                                                                     \
        _Pragma("unroll") for (int jj = 0; jj < 2; ++jj) {                              \
            u64 c  = s_[2][jj+2], pl = s_[2][jj+1], pr = s_[2][jj+3];                   \
            u64 l1 = (c<<1)|(pl>>63), l2 = (c<<2)|(pl>>62);                             \
            u64 r1 = (c>>1)|(pr<<63), r2 = (c>>2)|(pr<<62);                             \
            u64 u_ = s_[1][jj+2], ul = (u_<<1)|(s_[1][jj+1]>>63), ur = (u_>>1)|(s_[1][jj+3]<<63);\
            u64 d_ = s_[3][jj+2], dl = (d_<<1)|(s_[3][jj+1]>>63), dr = (d_>>1)|(s_[3][jj+3]<<63);\
            u64 u2 = s_[0][jj+2], d2 = s_[4][jj+2];                                     \
            u64 r_ = ISDIL ? (c|l1|l2|r1|r2|u_|ul|ur|d_|dl|dr|u2|d2)                    \
                           : (c&l1&l2&r1&r2&u_&ul&ur&d_&dl&dr&u2&d2);                   \
            if (jj == 0) rA = r_; else rB = r_;                                         \
        }                                                                               \
        ulonglong2 st; st.x = rA; st.y = rB;                                            \
        *reinterpret_cast<ulonglong2*>(&DST[ar][wb]) = st;                              \
        if (SETREG) { myw0 = rA; myw1 = rB; }                                           \
    }                                                                                   \
    __syncthreads();                                                                    \
} while (0)

// Thinning sub-iteration: center pair from registers; edge words via b64 reads.
#define THIN_SUB(SRC, DST, SUB, LO, HI) do {                                            \
    if (act && lr >= (LO) && lr < (HI)) {                                               \
        ulonglong2 u1 = *reinterpret_cast<const ulonglong2*>(&SRC[ar-1][wb]);           \
        u64 u_l = SRC[ar-1][wb-1];                                                      \
        u64 u_r = SRC[ar-1][wb+2];                                                      \
        ulonglong2 d1 = *reinterpret_cast<const ulonglong2*>(&SRC[ar+1][wb]);           \
        u64 d_l = SRC[ar+1][wb-1];                                                      \
        u64 d_r = SRC[ar+1][wb+2];                                                      \
        u64 c_l = SRC[ar][wb-1];                                                        \
        u64 c_r = SRC[ar][wb+2];                                                        \
        u64 rA, rB;                                                                     \
        { u64 c = myw0, pl = c_l, pr = myw1;                                            \
          u64 N  = u1.x, S = d1.x;                                                      \
          u64 E  = (c>>1)|(pr<<63),      Wn = (c<<1)|(pl>>63);                          \
          u64 NE = (u1.x>>1)|(u1.y<<63), NW = (u1.x<<1)|(u_l>>63);                      \
          u64 SE = (d1.x>>1)|(d1.y<<63), SW = (d1.x<<1)|(d_l>>63);                      \
          rA = zs_word(c, N, NE, E, SE, S, SW, Wn, NW, SUB); }                          \
        { u64 c = myw1, pl = myw0, pr = c_r;                                            \
          u64 N  = u1.y, S = d1.y;                                                      \
          u64 E  = (c>>1)|(pr<<63),      Wn = (c<<1)|(pl>>63);                          \
          u64 NE = (u1.y>>1)|(u_r<<63),  NW = (u1.y<<1)|(u1.x>>63);                     \
          u64 SE = (d1.y>>1)|(d_r<<63),  SW = (d1.y<<1)|(d1.x>>63);                     \
          rB = zs_word(c, N, NE, E, SE, S, SW, Wn, NW, SUB); }                          \
        ulonglong2 st; st.x = rA; st.y = rB;                                            \
        *reinterpret_cast<ulonglong2*>(&DST[ar][wb]) = st;                              \
        myw0 = rA; myw1 = rB;                                                           \
    }                                                                                   \
    __syncthreads();                                                                    \
} while (0)

// ---------------- kernel 2: closing + 48x thinning in LDS ----------------
// One block per (slice, 128-row band). 1024 threads = 4 threads/row
// (2 u64 words each) = 16 waves; 45KB LDS -> 2 blocks/CU co-resident.
__global__ __launch_bounds__(NTHR, 8)
void thin_kernel(const u64* __restrict__ bits, int* __restrict__ out) {
    __shared__ u64 bufA[ARR][PITCH];
    __shared__ u64 bufB[ARR][PITCH];

    const int blk  = blockIdx.x;
    const int z    = blk >> 2;       // slice
    const int band = blk & 3;
    const int r0   = band * BH;      // first output row
    const int la   = (r0 - HALO > 0) ? (r0 - HALO) : 0;
    const int lb   = (r0 + BH + HALO < HH) ? (r0 + BH + HALO) : HH;
    const int nrows = lb - la;       // live rows (<= 232)
    const int ob0  = r0 - la;        // local output start (0 or 52)

    const int t  = threadIdx.x;
    const int lr = t >> 2;           // row handled by this thread (0..255)
    const int q  = t & 3;            // word-pair index 0..3
    const int wb = 2 * q + WOFF;     // LDS idx of first owned word
    const int ar = lr + 2;           // array row (2 guard rows at top)
    const bool act = (lr < nrows);

    u64 myw0 = 0, myw1 = 0;          // register-resident center words

    // ---- zero both buffers (guards/pads must be 0 in both) ----
    {
        u64* fa = &bufA[0][0];
        u64* fb = &bufB[0][0];
        for (int i = t; i < ARR * PITCH; i += NTHR) { fa[i] = 0; fb[i] = 0; }
    }
    __syncthreads();

    // ---- load packed raw mask into bufA live area ----
    if (act) {
        const u64* src = bits + ((long)(z * HH + la + lr)) * WPR + 2 * q;
        ulonglong2 v = *reinterpret_cast<const ulonglong2*>(src);
        *reinterpret_cast<ulonglong2*>(&bufA[ar][wb]) = v;
    }
    __syncthreads();

    // ---- closing: dilation (A->B) then erosion (B->A, seeds registers) ----
    CLOSE_PHASE(bufA, bufB, 1, 0);
    CLOSE_PHASE(bufB, bufA, 0, 1);

    // ---- 48 Zhang-Suen sub-iterations, shrinking active range ----
    #pragma unroll 1
    for (int it2 = 0; it2 < NSUB / 2; ++it2) {
        {
            int hw = NSUB - (2 * it2 + 1);
            int lo = ob0 - hw;       if (lo < 0) lo = 0;
            int hi = ob0 + BH + hw;  if (hi > nrows) hi = nrows;
            THIN_SUB(bufA, bufB, 0, lo, hi);
        }
        {
            int hw = NSUB - (2 * it2 + 2);
            int lo = ob0 - hw;       if (lo < 0) lo = 0;
            int hi = ob0 + BH + hw;  if (hi > nrows) hi = nrows;
            THIN_SUB(bufB, bufA, 1, lo, hi);
        }
    }
    // final state is in bufA

    // ---- expand band rows [r0, r0+BH) to int32 0/1, coalesced int4 stores ----
    const long slice_base = (long)z * HH * WWID;
    for (int e = t; e < BH * (WWID / 4); e += NTHR) {
        int rr  = e >> 7;
        int x4  = e & 127;
        int gr  = r0 + rr;
        int arr = (gr - la) + 2;
        int col = x4 * 4;
        u64 w  = bufA[arr][WOFF + (col >> 6)];
        int sh = col & 63;
        int4 f;
        f.x = (int)((w >> (sh + 0)) & 1ull);
        f.y = (int)((w >> (sh + 1)) & 1ull);
        f.z = (int)((w >> (sh + 2)) & 1ull);
        f.w = (int)((w >> (sh + 3)) & 1ull);
        *reinterpret_cast<int4*>(out + slice_base + (long)gr * WWID + col) = f;
    }
}

extern "C" void kernel_launch(void* const* d_in, const int* in_sizes, int n_in,
                              void* d_out, int out_size, void* d_ws, size_t ws_size,
                              hipStream_t stream) {
    const float* in   = (const float*)d_in[0];
    int*         out  = (int*)d_out;
    u64*         bits = (u64*)d_ws;   // 2 MiB scratch

    pack_kernel<<<16384, 256, 0, stream>>>(in, bits);
    thin_kernel<<<DD * BANDS, NTHR, 0, stream>>>(bits, out);
}